// Round 5
// baseline (883.945 us; speedup 1.0000x reference)
//
#include <hip/hip_runtime.h>

#define RL(x) __builtin_amdgcn_readfirstlane(x)

// Unaligned-tolerant 16B load (align-4). HW handles unaligned global loads;
// worst case the compiler splits — either way correct, per-lane, pipelined.
struct F4 { float x, y, z, w; };
static __device__ __forceinline__ F4 ld4(const float* p) { return *(const F4*)p; }

// ---------------- weight prep: transpose conv2/conv3 weights to lane-coalesced layouts ----
// wt2[((ic*4+q)*64+oc)*4+c] = w2[oc][ic][q*4+c]           (32*64*16  = 32768)
// wt3[((ic*3+q)*64+oc)*4+c] = (q*4+c<9) ? w3[oc][ic][q*4+c] : 0   (64*64*12 = 49152)
__global__ __launch_bounds__(256) void wprep_k(const float* __restrict__ w2,
                                               const float* __restrict__ w3,
                                               float* __restrict__ wt2,
                                               float* __restrict__ wt3) {
  int i = blockIdx.x * 256 + threadIdx.x;
  if (i < 32768) {
    int oc = i >> 9, rem = i & 511;
    int ic = rem >> 4, t = rem & 15;
    wt2[((ic * 4 + (t >> 2)) * 64 + oc) * 4 + (t & 3)] = w2[i];
  }
  if (i < 49152) {
    int oc = i / 768, rem = i - oc * 768;
    int ic = rem / 12, t = rem - ic * 12;
    float v = (t < 9) ? w3[oc * 576 + ic * 9 + t] : 0.f;
    wt3[((ic * 3 + (t >> 2)) * 64 + oc) * 4 + (t & 3)] = v;
  }
}

// ---------------- conv1: x[1024,4,84,84] -> c1[1024,32,20,20], k=8, s=4 ----------------
// Pixels on lanes, weights from LDS broadcast (proven in R2/R3 — unchanged).
__global__ __launch_bounds__(256, 2) void conv1_k(const float* __restrict__ x,
                                                  const float* __restrict__ w,    // [32,4,8,8]
                                                  const float* __restrict__ bias,
                                                  float* __restrict__ out) {
  __shared__ float wl[8192];
  const int b    = blockIdx.x;
  const int tid  = threadIdx.x;
  const int lane = tid & 63;
  const int g    = RL(tid >> 6);

#pragma unroll
  for (int i = 0; i < 32; ++i) {
    int idx = tid + i * 256;
    int oc = idx >> 8, rem = idx & 255;
    wl[(rem >> 3) * 256 + oc * 8 + (rem & 7)] = w[idx];
  }
  __syncthreads();

  int pv[7], ib[7];
#pragma unroll
  for (int s = 0; s < 7; ++s) {
    int p = lane + 64 * s;
    pv[s] = (p < 400);
    if (p > 399) p = 399;
    int py = p / 20, px = p - py * 20;
    ib[s] = py * 336 + px * 4;
  }

  float acc[7][8];
#pragma unroll
  for (int s = 0; s < 7; ++s)
#pragma unroll
    for (int j = 0; j < 8; ++j) acc[s][j] = 0.f;

  const float* xb = x + b * 28224;
#pragma unroll 1
  for (int ic = 0; ic < 4; ++ic) {
#pragma unroll 1
    for (int ky = 0; ky < 8; ++ky) {
      const float* wp = &wl[(ic * 8 + ky) * 256 + g * 64];
      float wr[8][8];
#pragma unroll
      for (int j = 0; j < 8; ++j) {
        float4 w0 = *(const float4*)(wp + j * 8);
        float4 w1 = *(const float4*)(wp + j * 8 + 4);
        wr[j][0]=w0.x; wr[j][1]=w0.y; wr[j][2]=w0.z; wr[j][3]=w0.w;
        wr[j][4]=w1.x; wr[j][5]=w1.y; wr[j][6]=w1.z; wr[j][7]=w1.w;
      }
      const float* rp = xb + ic * 7056 + ky * 84;
#pragma unroll
      for (int s = 0; s < 7; ++s) {
        float4 a = *(const float4*)(rp + ib[s]);
        float4 c = *(const float4*)(rp + ib[s] + 4);
        float in8[8] = {a.x, a.y, a.z, a.w, c.x, c.y, c.z, c.w};
#pragma unroll
        for (int j = 0; j < 8; ++j)
#pragma unroll
          for (int kx = 0; kx < 8; ++kx)
            acc[s][j] = fmaf(in8[kx], wr[j][kx], acc[s][j]);
      }
    }
  }

  const float inv256 = 1.0f / 256.0f;
#pragma unroll
  for (int j = 0; j < 8; ++j) {
    float bj = bias[g * 8 + j];
    float* op = out + (b * 32 + g * 8 + j) * 400;
#pragma unroll
    for (int s = 0; s < 7; ++s) {
      if (pv[s]) {
        float v = acc[s][j] * inv256 + bj;
        op[lane + 64 * s] = v > 0.f ? v : 0.f;
      }
    }
  }
}

// ---------------- conv2: c1[1024,32,20,20] -> c2[1024,64,9,9], k=4, s=2 ----------------
// Checkerboard lanes: o=tid&7 (oc), p=(tid>>3)&7 (px). Wave w covers oc
// w*16+i*8+o (i<2); px chunks p_flat=p+8k (k<11, 81 valid). Weights per-lane
// coalesced from wt2 (128B contiguous per 8 o-lanes), inputs per-lane 16B row
// segments. No LDS, no broadcast, no barrier.
__global__ __launch_bounds__(256, 4) void conv2_k(const float* __restrict__ in,
                                                  const float* __restrict__ wt,   // [ic][q][oc][4]
                                                  const float* __restrict__ bias,
                                                  float* __restrict__ out) {
  const int b   = blockIdx.x;
  const int tid = threadIdx.x;
  const int o   = tid & 7;
  const int p   = (tid >> 3) & 7;
  const int wv  = RL(tid >> 6);
  const int oc0 = wv * 16 + o;         // oc for i: oc0 + 8*i

  int ib[11];
#pragma unroll
  for (int k = 0; k < 11; ++k) {
    int pf = p + 8 * k;
    if (pf > 80) pf = 80;
    int py = pf / 9, px = pf - py * 9;
    ib[k] = 40 * py + 2 * px;          // (2py)*20 + 2px
  }

  float acc[2][11];
#pragma unroll
  for (int i = 0; i < 2; ++i)
#pragma unroll
    for (int k = 0; k < 11; ++k) acc[i][k] = 0.f;

  const float* inb = in + b * 12800;
  const float4* wt4 = (const float4*)wt;

#pragma unroll 1
  for (int ic = 0; ic < 32; ++ic) {
    float wk[2][16];
#pragma unroll
    for (int i = 0; i < 2; ++i)
#pragma unroll
      for (int q = 0; q < 4; ++q) {
        float4 t = wt4[(ic * 4 + q) * 64 + oc0 + 8 * i];
        wk[i][q*4]=t.x; wk[i][q*4+1]=t.y; wk[i][q*4+2]=t.z; wk[i][q*4+3]=t.w;
      }
    const float* icp = inb + ic * 400;
#pragma unroll
    for (int ky = 0; ky < 4; ++ky) {
      const float* rp = icp + ky * 20;
      F4 in4[11];
#pragma unroll
      for (int k = 0; k < 11; ++k) in4[k] = ld4(rp + ib[k]);
#pragma unroll
      for (int k = 0; k < 11; ++k) {
        float iv[4] = {in4[k].x, in4[k].y, in4[k].z, in4[k].w};
#pragma unroll
        for (int i = 0; i < 2; ++i)
#pragma unroll
          for (int kx = 0; kx < 4; ++kx)
            acc[i][k] = fmaf(iv[kx], wk[i][ky * 4 + kx], acc[i][k]);
      }
    }
  }

#pragma unroll
  for (int i = 0; i < 2; ++i) {
    const int oc = oc0 + 8 * i;
    const float bj = bias[oc];
    float* op = out + (b * 64 + oc) * 81;
#pragma unroll
    for (int k = 0; k < 11; ++k) {
      int pf = p + 8 * k;
      if (pf < 81) {
        float v = acc[i][k] + bj;
        op[pf] = v > 0.f ? v : 0.f;
      }
    }
  }
}

// ---------------- conv3: c2[1024,64,9,9] -> c3[1024,64,7,7], k=3, s=1 ----------------
// Same checkerboard structure: o=oc lane, p=px lane; p_flat=p+8k (k<7, 49 valid).
// Weights from zero-padded wt3 (12/ic per oc, flat t=ky*3+kx).
__global__ __launch_bounds__(256, 4) void conv3_k(const float* __restrict__ in,
                                                  const float* __restrict__ wt,   // [ic][q][oc][4]
                                                  const float* __restrict__ bias,
                                                  float* __restrict__ out) {
  const int b   = blockIdx.x;
  const int tid = threadIdx.x;
  const int o   = tid & 7;
  const int p   = (tid >> 3) & 7;
  const int wv  = RL(tid >> 6);
  const int oc0 = wv * 16 + o;

  int ib[7];
#pragma unroll
  for (int k = 0; k < 7; ++k) {
    int pf = p + 8 * k;
    if (pf > 48) pf = 48;
    int py = pf / 7, px = pf - py * 7;
    ib[k] = py * 9 + px;
  }

  float acc[2][7];
#pragma unroll
  for (int i = 0; i < 2; ++i)
#pragma unroll
    for (int k = 0; k < 7; ++k) acc[i][k] = 0.f;

  const float* inb = in + b * 5184;
  const float4* wt4 = (const float4*)wt;

#pragma unroll 1
  for (int ic = 0; ic < 64; ++ic) {
    float wk[2][12];
#pragma unroll
    for (int i = 0; i < 2; ++i)
#pragma unroll
      for (int q = 0; q < 3; ++q) {
        float4 t = wt4[(ic * 3 + q) * 64 + oc0 + 8 * i];
        wk[i][q*4]=t.x; wk[i][q*4+1]=t.y; wk[i][q*4+2]=t.z; wk[i][q*4+3]=t.w;
      }
    const float* icp = inb + ic * 81;
#pragma unroll
    for (int ky = 0; ky < 3; ++ky) {
      const float* rp = icp + ky * 9;
      F4 in4[7];
#pragma unroll
      for (int k = 0; k < 7; ++k) in4[k] = ld4(rp + ib[k]);
#pragma unroll
      for (int k = 0; k < 7; ++k) {
        float iv[3] = {in4[k].x, in4[k].y, in4[k].z};
#pragma unroll
        for (int i = 0; i < 2; ++i)
#pragma unroll
          for (int kx = 0; kx < 3; ++kx)
            acc[i][k] = fmaf(iv[kx], wk[i][ky * 3 + kx], acc[i][k]);
      }
    }
  }

#pragma unroll
  for (int i = 0; i < 2; ++i) {
    const int oc = oc0 + 8 * i;
    const float bj = bias[oc];
    float* op = out + b * 3136 + oc * 49;
#pragma unroll
    for (int k = 0; k < 7; ++k) {
      int pf = p + 8 * k;
      if (pf < 49) {
        float v = acc[i][k] + bj;
        op[pf] = v > 0.f ? v : 0.f;
      }
    }
  }
}

// ---------------- fc1a: c3[1024][3136] @ fw1[3136][256] -> partial[8][1024][256] ----------------
__global__ __launch_bounds__(256) void fc1a_k(const float* __restrict__ a,
                                              const float* __restrict__ w,
                                              float* __restrict__ part) {
  __shared__ float al[56][20];
  const int b0  = blockIdx.x * 16;
  const int k0  = blockIdx.y * 392;
  const int tid = threadIdx.x;
  const int jj  = tid & 63;
  const int ib  = RL(tid >> 6);

  float acc[4][4];
#pragma unroll
  for (int r = 0; r < 4; ++r)
#pragma unroll
    for (int c = 0; c < 4; ++c) acc[r][c] = 0.f;

#pragma unroll 1
  for (int t = 0; t < 7; ++t) {
    __syncthreads();
#pragma unroll
    for (int z = 0; z < 4; ++z) {
      int idx = tid + z * 256;
      if (idx < 896) {
        int i = idx / 56, kk = idx - i * 56;
        al[kk][i] = a[(b0 + i) * 3136 + k0 + t * 56 + kk];
      }
    }
    __syncthreads();
#pragma unroll 2
    for (int kk = 0; kk < 56; ++kk) {
      float4 wv4 = *(const float4*)&w[(k0 + t * 56 + kk) * 256 + jj * 4];
      float4 av  = *(const float4*)&al[kk][ib * 4];
      float avr[4] = {av.x, av.y, av.z, av.w};
#pragma unroll
      for (int r = 0; r < 4; ++r) {
        acc[r][0] = fmaf(avr[r], wv4.x, acc[r][0]);
        acc[r][1] = fmaf(avr[r], wv4.y, acc[r][1]);
        acc[r][2] = fmaf(avr[r], wv4.z, acc[r][2]);
        acc[r][3] = fmaf(avr[r], wv4.w, acc[r][3]);
      }
    }
  }
#pragma unroll
  for (int r = 0; r < 4; ++r) {
    float4 v = {acc[r][0], acc[r][1], acc[r][2], acc[r][3]};
    *(float4*)&part[(blockIdx.y * 1024 + b0 + ib * 4 + r) * 256 + jj * 4] = v;
  }
}

// ---------------- fc1b: reduce 8 partials + bias + relu -> h[1024][256] ----------------
__global__ __launch_bounds__(256) void fc1b_k(const float* __restrict__ part,
                                              const float* __restrict__ bias,
                                              float* __restrict__ h) {
  int idx = blockIdx.x * 256 + threadIdx.x;
  int j = idx & 255;
  float s = bias[j];
#pragma unroll
  for (int c = 0; c < 8; ++c) s += part[c * 262144 + idx];
  h[idx] = s > 0.f ? s : 0.f;
}

// ---------------- fc2 + softmax + dist/res ----------------
__global__ __launch_bounds__(256) void fc2_k(const float* __restrict__ h,
                                             const float* __restrict__ w,   // [256][51]
                                             const float* __restrict__ bias,
                                             const float* __restrict__ z,
                                             float* __restrict__ dist,      // [1024][6][51]
                                             float* __restrict__ res) {     // [1024][6]
  const int tid = threadIdx.x;
  const int j   = tid & 63;
  const int b   = blockIdx.x * 4 + RL(tid >> 6);
  const float* hb = h + b * 256;
  const int jc = j < 51 ? j : 50;
  float acc = bias[jc];
#pragma unroll 4
  for (int k = 0; k < 256; ++k)
    acc = fmaf(hb[k], w[k * 51 + jc], acc);
  float logit = (j < 51) ? acc : -1e30f;
  float m = logit;
#pragma unroll
  for (int o = 32; o > 0; o >>= 1) m = fmaxf(m, __shfl_xor(m, o, 64));
  float e = (j < 51) ? __expf(logit - m) : 0.f;
  float ssum = e;
#pragma unroll
  for (int o = 32; o > 0; o >>= 1) ssum += __shfl_xor(ssum, o, 64);
  float p = e / ssum;
  float zv = (j < 51) ? z[jc] : 0.f;
  float rz = p * zv;
#pragma unroll
  for (int o = 32; o > 0; o >>= 1) rz += __shfl_xor(rz, o, 64);
  if (j < 51) {
    float* db = dist + b * 6 * 51 + j;
#pragma unroll
    for (int n = 0; n < 6; ++n) db[n * 51] = p;
  }
  if (j < 6) res[b * 6 + j] = rz;
}

extern "C" void kernel_launch(void* const* d_in, const int* in_sizes, int n_in,
                              void* d_out, int out_size, void* d_ws, size_t ws_size,
                              hipStream_t stream) {
  const float* x   = (const float*)d_in[0];
  const float* cw1 = (const float*)d_in[1];
  const float* cb1 = (const float*)d_in[2];
  const float* cw2 = (const float*)d_in[3];
  const float* cb2 = (const float*)d_in[4];
  const float* cw3 = (const float*)d_in[5];
  const float* cb3 = (const float*)d_in[6];
  const float* fw1 = (const float*)d_in[7];
  const float* fb1 = (const float*)d_in[8];
  const float* fw2 = (const float*)d_in[9];
  const float* fb2 = (const float*)d_in[10];
  const float* z   = (const float*)d_in[11];

  float* ws = (float*)d_ws;
  float* c1 = ws;                  // 1024*32*400
  float* c2 = ws + 13107200;       // 1024*64*81
  float* c3 = ws;                  // reuses dead c1
  float* pw = ws + 13107200;       // 8*1024*256, reuses dead c2
  float* h  = ws + 15204352;       // 1024*256

  // Transposed weights live in d_out (319488 floats >= 81920); fc2 overwrites
  // d_out at the very end, after the last read of wt3 (conv3).
  float* wt2 = (float*)d_out;            // 32768 floats
  float* wt3 = (float*)d_out + 32768;    // 49152 floats

  float* dist = (float*)d_out;
  float* res  = dist + 1024 * 6 * 51;

  wprep_k<<<192, 256, 0, stream>>>(cw2, cw3, wt2, wt3);
  conv1_k<<<1024, 256, 0, stream>>>(x, cw1, cb1, c1);
  conv2_k<<<1024, 256, 0, stream>>>(c1, wt2, cb2, c2);
  conv3_k<<<1024, 256, 0, stream>>>(c2, wt3, cb3, c3);
  fc1a_k<<<dim3(64, 8), 256, 0, stream>>>(c3, fw1, pw);
  fc1b_k<<<1024, 256, 0, stream>>>(pw, fb1, h);
  fc2_k<<<256, 256, 0, stream>>>(h, fw2, fb2, z, dist, res);
}

// Round 6
// 645.438 us; speedup vs baseline: 1.3695x; 1.3695x over previous
//
#include <hip/hip_runtime.h>
#include <hip/hip_fp16.h>

#define RL(x) __builtin_amdgcn_readfirstlane(x)

// ---------------- weight prep: conv2/conv3 weights -> [ic][ky][ocg][o][kx] (uniform-contiguous) ----
// wt2n[((ic*4+ky)*8+ocg)*32 + o*4+kx] = w2[(ocg*8+o)*512 + ic*16 + ky*4 + kx]   (32768)
// wt3n[((ic*3+ky)*8+ocg)*24 + o*3+kx] = w3[(ocg*8+o)*576 + ic*9  + ky*3 + kx]   (36864)
__global__ __launch_bounds__(256) void wprep_k(const float* __restrict__ w2,
                                               const float* __restrict__ w3,
                                               float* __restrict__ wt2,
                                               float* __restrict__ wt3) {
  int i = blockIdx.x * 256 + threadIdx.x;
  if (i < 32768) {
    int o4 = i & 31, o = o4 >> 2, kx = o4 & 3;
    int r = i >> 5, ocg = r & 7, r2 = r >> 3, ky = r2 & 3, ic = r2 >> 2;
    wt2[i] = w2[(ocg * 8 + o) * 512 + ic * 16 + ky * 4 + kx];
  }
  if (i < 36864) {
    int o3 = i % 24, o = o3 / 3, kx = o3 - o * 3;
    int r = i / 24, ocg = r & 7, r2 = r >> 3, ky = r2 % 3, ic = r2 / 3;
    wt3[i] = w3[(ocg * 8 + o) * 576 + ic * 9 + ky * 3 + kx];
  }
}

// ---------------- conv1: x[1024,4,84,84] -> c1h[b][32*400] fp16, k=8, s=4 ----------------
// Pixels on lanes, weights from LDS broadcast (proven structure; fp16 output).
__global__ __launch_bounds__(256, 2) void conv1_k(const float* __restrict__ x,
                                                  const float* __restrict__ w,    // [32,4,8,8]
                                                  const float* __restrict__ bias,
                                                  __half* __restrict__ out) {
  __shared__ float wl[8192];
  const int b    = blockIdx.x;
  const int tid  = threadIdx.x;
  const int lane = tid & 63;
  const int g    = RL(tid >> 6);

#pragma unroll
  for (int i = 0; i < 32; ++i) {
    int idx = tid + i * 256;
    int oc = idx >> 8, rem = idx & 255;
    wl[(rem >> 3) * 256 + oc * 8 + (rem & 7)] = w[idx];
  }
  __syncthreads();

  int pv[7], ib[7];
#pragma unroll
  for (int s = 0; s < 7; ++s) {
    int p = lane + 64 * s;
    pv[s] = (p < 400);
    if (p > 399) p = 399;
    int py = p / 20, px = p - py * 20;
    ib[s] = py * 336 + px * 4;
  }

  float acc[7][8];
#pragma unroll
  for (int s = 0; s < 7; ++s)
#pragma unroll
    for (int j = 0; j < 8; ++j) acc[s][j] = 0.f;

  const float* xb = x + b * 28224;
#pragma unroll 1
  for (int ic = 0; ic < 4; ++ic) {
#pragma unroll 1
    for (int ky = 0; ky < 8; ++ky) {
      const float* wp = &wl[(ic * 8 + ky) * 256 + g * 64];
      float wr[8][8];
#pragma unroll
      for (int j = 0; j < 8; ++j) {
        float4 w0 = *(const float4*)(wp + j * 8);
        float4 w1 = *(const float4*)(wp + j * 8 + 4);
        wr[j][0]=w0.x; wr[j][1]=w0.y; wr[j][2]=w0.z; wr[j][3]=w0.w;
        wr[j][4]=w1.x; wr[j][5]=w1.y; wr[j][6]=w1.z; wr[j][7]=w1.w;
      }
      const float* rp = xb + ic * 7056 + ky * 84;
#pragma unroll
      for (int s = 0; s < 7; ++s) {
        float4 a = *(const float4*)(rp + ib[s]);
        float4 c = *(const float4*)(rp + ib[s] + 4);
        float in8[8] = {a.x, a.y, a.z, a.w, c.x, c.y, c.z, c.w};
#pragma unroll
        for (int j = 0; j < 8; ++j)
#pragma unroll
          for (int kx = 0; kx < 8; ++kx)
            acc[s][j] = fmaf(in8[kx], wr[j][kx], acc[s][j]);
      }
    }
  }

  const float inv256 = 1.0f / 256.0f;
#pragma unroll
  for (int j = 0; j < 8; ++j) {
    float bj = bias[g * 8 + j];
    __half* op = out + (b * 32 + g * 8 + j) * 400;
#pragma unroll
    for (int s = 0; s < 7; ++s) {
      if (pv[s]) {
        float v = acc[s][j] * inv256 + bj;
        op[lane + 64 * s] = __float2half(v > 0.f ? v : 0.f);
      }
    }
  }
}

// ---------------- t1: transpose c1h[1024][12800] -> c1t[12800][1024] (fp16) ----------------
__global__ __launch_bounds__(256) void t1_k(const __half* __restrict__ in,
                                            __half* __restrict__ out) {
  __shared__ __half t[64][65];
  const int kb = blockIdx.x * 64;   // 200 tiles
  const int bb = blockIdx.y * 64;   // 16 tiles
  const int lane = threadIdx.x & 63;
  const int ty   = threadIdx.x >> 6;
#pragma unroll
  for (int r = ty; r < 64; r += 4)
    t[r][lane] = in[(bb + r) * 12800 + kb + lane];
  __syncthreads();
#pragma unroll
  for (int r = ty; r < 64; r += 4)
    out[(kb + r) * 1024 + bb + lane] = t[lane][r];
}

// ---------------- conv2: c1t[12800][1024] -> c2t[5184][1024], k=4, s=2 (fp16 io) ----------
// Batch on lanes. Block = 1 wave; bid -> (bg, opy, ocg). acc[8 oc][9 ox] fp32.
// Inputs: coalesced ushort loads; weights: wave-uniform s_loads (SGPR FMA operand).
__global__ __launch_bounds__(64, 2) void conv2_k(const __half* __restrict__ in,
                                                 const float* __restrict__ wt,   // wt2n
                                                 const float* __restrict__ bias,
                                                 __half* __restrict__ out) {
  const int bid = blockIdx.x;            // 1152 = (bg*9 + opy)*8 + ocg
  const int ocg = bid & 7;
  const int r   = bid >> 3;
  const int opy = r % 9;
  const int bg  = r / 9;
  const int lane = threadIdx.x;

  float acc[8][9];
#pragma unroll
  for (int o = 0; o < 8; ++o)
#pragma unroll
    for (int ox = 0; ox < 9; ++ox) acc[o][ox] = 0.f;

  const __half* ib = in + bg * 64 + lane;

#pragma unroll 1
  for (int ic = 0; ic < 32; ++ic) {
#pragma unroll
    for (int ky = 0; ky < 4; ++ky) {
      const float* wp = wt + ((ic * 4 + ky) * 8 + ocg) * 32;
      float wk[32];
#pragma unroll
      for (int q = 0; q < 32; ++q) wk[q] = wp[q];
      const __half* rp = ib + (ic * 400 + (2 * opy + ky) * 20) * 1024;
      float iv[20];
#pragma unroll
      for (int q = 0; q < 20; ++q) iv[q] = __half2float(rp[q * 1024]);
#pragma unroll
      for (int o = 0; o < 8; ++o)
#pragma unroll
        for (int ox = 0; ox < 9; ++ox)
#pragma unroll
          for (int kx = 0; kx < 4; ++kx)
            acc[o][ox] = fmaf(iv[2 * ox + kx], wk[o * 4 + kx], acc[o][ox]);
    }
  }

#pragma unroll
  for (int o = 0; o < 8; ++o) {
    const int oc = ocg * 8 + o;
    const float bj = bias[oc];
#pragma unroll
    for (int ox = 0; ox < 9; ++ox) {
      float v = acc[o][ox] + bj;
      out[(oc * 81 + opy * 9 + ox) * 1024 + bg * 64 + lane] =
          __float2half(v > 0.f ? v : 0.f);
    }
  }
}

// ---------------- conv3: c2t[5184][1024] -> c3t[3136][1024], k=3, s=1 (fp16 io) ----------
__global__ __launch_bounds__(64, 2) void conv3_k(const __half* __restrict__ in,
                                                 const float* __restrict__ wt,   // wt3n
                                                 const float* __restrict__ bias,
                                                 __half* __restrict__ out) {
  const int bid = blockIdx.x;            // 896 = (bg*7 + opy)*8 + ocg
  const int ocg = bid & 7;
  const int r   = bid >> 3;
  const int opy = r % 7;
  const int bg  = r / 7;
  const int lane = threadIdx.x;

  float acc[8][7];
#pragma unroll
  for (int o = 0; o < 8; ++o)
#pragma unroll
    for (int ox = 0; ox < 7; ++ox) acc[o][ox] = 0.f;

  const __half* ib = in + bg * 64 + lane;

#pragma unroll 1
  for (int ic = 0; ic < 64; ++ic) {
#pragma unroll
    for (int ky = 0; ky < 3; ++ky) {
      const float* wp = wt + ((ic * 3 + ky) * 8 + ocg) * 24;
      float wk[24];
#pragma unroll
      for (int q = 0; q < 24; ++q) wk[q] = wp[q];
      const __half* rp = ib + (ic * 81 + (opy + ky) * 9) * 1024;
      float iv[9];
#pragma unroll
      for (int q = 0; q < 9; ++q) iv[q] = __half2float(rp[q * 1024]);
#pragma unroll
      for (int o = 0; o < 8; ++o)
#pragma unroll
        for (int ox = 0; ox < 7; ++ox)
#pragma unroll
          for (int kx = 0; kx < 3; ++kx)
            acc[o][ox] = fmaf(iv[ox + kx], wk[o * 3 + kx], acc[o][ox]);
    }
  }

#pragma unroll
  for (int o = 0; o < 8; ++o) {
    const int oc = ocg * 8 + o;
    const float bj = bias[oc];
#pragma unroll
    for (int ox = 0; ox < 7; ++ox) {
      float v = acc[o][ox] + bj;
      out[(oc * 49 + opy * 7 + ox) * 1024 + bg * 64 + lane] =
          __float2half(v > 0.f ? v : 0.f);
    }
  }
}

// ---------------- fc1a: c3t[3136][1024] @ fw1[3136][256] -> part[8][256][1024] ------------
// Batch on lanes; wave = (bg, jg of 16 j, kc of 392 k). A coalesced, W uniform s_loads.
__global__ __launch_bounds__(64, 2) void fc1a_k(const __half* __restrict__ a,
                                                const float* __restrict__ w,
                                                float* __restrict__ part) {
  const int bid = blockIdx.x;            // 2048 = (bg*16 + jg)*8 + kc
  const int kc = bid & 7;
  const int r  = bid >> 3;
  const int jg = r & 15;
  const int bg = r >> 4;
  const int lane = threadIdx.x;

  float acc[16];
#pragma unroll
  for (int j = 0; j < 16; ++j) acc[j] = 0.f;

  const __half* ap = a + kc * 392 * 1024 + bg * 64 + lane;
  const float* wp0 = w + kc * 392 * 256 + jg * 16;

#pragma unroll 2
  for (int k = 0; k < 392; ++k) {
    float av = __half2float(ap[k * 1024]);
    const float* wp = wp0 + k * 256;
#pragma unroll
    for (int j = 0; j < 16; ++j) acc[j] = fmaf(av, wp[j], acc[j]);
  }
#pragma unroll
  for (int j = 0; j < 16; ++j)
    part[(kc * 256 + jg * 16 + j) * 1024 + bg * 64 + lane] = acc[j];
}

// ---------------- fc1b: reduce 8 partials + bias + relu -> h_t[256][1024] ----------------
__global__ __launch_bounds__(256) void fc1b_k(const float* __restrict__ part,
                                              const float* __restrict__ bias,
                                              float* __restrict__ h) {
  int idx = blockIdx.x * 256 + threadIdx.x;   // j*1024 + b
  float s = bias[idx >> 10];
#pragma unroll
  for (int c = 0; c < 8; ++c) s += part[c * 262144 + idx];
  h[idx] = s > 0.f ? s : 0.f;
}

// ---------------- fc2 + softmax + dist/res (reads h_t[k][b]) ----------------
__global__ __launch_bounds__(256) void fc2_k(const float* __restrict__ h,     // [256][1024]
                                             const float* __restrict__ w,     // [256][51]
                                             const float* __restrict__ bias,
                                             const float* __restrict__ z,
                                             float* __restrict__ dist,        // [1024][6][51]
                                             float* __restrict__ res) {       // [1024][6]
  const int tid = threadIdx.x;
  const int j   = tid & 63;
  const int b   = blockIdx.x * 4 + RL(tid >> 6);
  const int jc = j < 51 ? j : 50;
  float acc = bias[jc];
#pragma unroll 4
  for (int k = 0; k < 256; ++k)
    acc = fmaf(h[k * 1024 + b], w[k * 51 + jc], acc);
  float logit = (j < 51) ? acc : -1e30f;
  float m = logit;
#pragma unroll
  for (int o = 32; o > 0; o >>= 1) m = fmaxf(m, __shfl_xor(m, o, 64));
  float e = (j < 51) ? __expf(logit - m) : 0.f;
  float ssum = e;
#pragma unroll
  for (int o = 32; o > 0; o >>= 1) ssum += __shfl_xor(ssum, o, 64);
  float p = e / ssum;
  float zv = (j < 51) ? z[jc] : 0.f;
  float rz = p * zv;
#pragma unroll
  for (int o = 32; o > 0; o >>= 1) rz += __shfl_xor(rz, o, 64);
  if (j < 51) {
    float* db = dist + b * 6 * 51 + j;
#pragma unroll
    for (int n = 0; n < 6; ++n) db[n * 51] = p;
  }
  if (j < 6) res[b * 6 + j] = rz;
}

extern "C" void kernel_launch(void* const* d_in, const int* in_sizes, int n_in,
                              void* d_out, int out_size, void* d_ws, size_t ws_size,
                              hipStream_t stream) {
  const float* x   = (const float*)d_in[0];
  const float* cw1 = (const float*)d_in[1];
  const float* cb1 = (const float*)d_in[2];
  const float* cw2 = (const float*)d_in[3];
  const float* cb2 = (const float*)d_in[4];
  const float* cw3 = (const float*)d_in[5];
  const float* cb3 = (const float*)d_in[6];
  const float* fw1 = (const float*)d_in[7];
  const float* fb1 = (const float*)d_in[8];
  const float* fw2 = (const float*)d_in[9];
  const float* fb2 = (const float*)d_in[10];
  const float* z   = (const float*)d_in[11];

  float* ws = (float*)d_ws;
  // float-offsets (fp16 buffers occupy half):
  // c1h : [0, 6553600)          1024*12800 halfs
  // c1t : [6553600, 13107200)   12800*1024 halfs
  // c2t : [13107200, 15761408)  5184*1024 halfs
  // c3t : [15761408, 17367040)  3136*1024 halfs
  // part: [0, 2097152)          8*256*1024 fp32 (reuses dead c1h)
  // h_t : [2097152, 2359296)    256*1024 fp32
  __half* c1h = (__half*)ws;
  __half* c1t = (__half*)(ws + 6553600);
  __half* c2t = (__half*)(ws + 13107200);
  __half* c3t = (__half*)(ws + 15761408);
  float*  pw  = ws;
  float*  h_t = ws + 2097152;

  // Transposed conv weights in d_out scratch (69632 <= 319488); dist written last.
  float* wt2n = (float*)d_out;
  float* wt3n = (float*)d_out + 32768;

  float* dist = (float*)d_out;
  float* res  = dist + 1024 * 6 * 51;

  wprep_k<<<144, 256, 0, stream>>>(cw2, cw3, wt2n, wt3n);
  conv1_k<<<1024, 256, 0, stream>>>(x, cw1, cb1, c1h);
  t1_k<<<dim3(200, 16), 256, 0, stream>>>(c1h, c1t);
  conv2_k<<<1152, 64, 0, stream>>>(c1t, wt2n, cb2, c2t);
  conv3_k<<<896, 64, 0, stream>>>(c2t, wt3n, cb3, c3t);
  fc1a_k<<<2048, 64, 0, stream>>>(c3t, fw1, pw);
  fc1b_k<<<1024, 256, 0, stream>>>(pw, fb1, h_t);
  fc2_k<<<256, 256, 0, stream>>>(h_t, fw2, fb2, z, dist, res);
}